// Round 5
// baseline (329.822 us; speedup 1.0000x reference)
//
#include <hip/hip_runtime.h>

#define HID 2048
#define NEXP 64
#define NTOK 16384
#define TM 32            // tokens per block (one 32-row MFMA tile)
#define NTHREADS 512     // 8 waves
#define TPW 4            // tokens per wave in epilogue (TM / 8)
#define NBLK (NTOK / TM) // 512
#define WS_W_OFF 1024    // W planes start here in d_ws
#define CHUNK_B 24576    // 4 ksteps * 3 planes * 2 halves * 1024 B

// out layout (f32): weights [0,32768) | indices [32768,65536) | aux 65536 | counts [65537,65601)
#define OUT_IDX_OFF (2 * NTOK)
#define OUT_AUX_OFF (4 * NTOK)
#define OUT_CNT_OFF (4 * NTOK + 1)

typedef __attribute__((ext_vector_type(8))) short bhalf8;    // 8 bf16 = 4 VGPRs (A/B frag)
typedef __attribute__((ext_vector_type(16))) float f32x16;   // 32x32 C/D frag

// async 1KB global->LDS stage: per-lane 16B source, LDS dest = wave-uniform base + lane*16
__device__ __forceinline__ void stage1k(const void* g, void* l) {
    __builtin_amdgcn_global_load_lds((const __attribute__((address_space(1))) void*)g,
                                     (__attribute__((address_space(3))) void*)l, 16, 0, 0);
}

// Exact 3-way RNE bf16 split (for W, precomputed): v == h1+h2+h3 exactly.
__device__ __forceinline__ void split3(float v, unsigned short& h1, unsigned short& h2, unsigned short& h3) {
    unsigned int u = __float_as_uint(v);
    unsigned int r1 = (u + 0x7FFFu + ((u >> 16) & 1u)) & 0xFFFF0000u;
    float f1 = __uint_as_float(r1);
    float d1 = v - f1;
    unsigned int u2 = __float_as_uint(d1);
    unsigned int r2 = (u2 + 0x7FFFu + ((u2 >> 16) & 1u)) & 0xFFFF0000u;
    float f2 = __uint_as_float(r2);
    float d2 = d1 - f2;
    h1 = (unsigned short)(r1 >> 16);
    h2 = (unsigned short)(r2 >> 16);
    h3 = (unsigned short)(__float_as_uint(d2) >> 16);
}

// Truncating 3-plane split of 8 fp32 -> three bf16x8 A-frags, in registers.
__device__ __forceinline__ void xsplit(float4 va, float4 vb, bhalf8& o1, bhalf8& o2, bhalf8& o3) {
    float f[8] = {va.x, va.y, va.z, va.w, vb.x, vb.y, vb.z, vb.w};
    union U { bhalf8 v; unsigned int u[4]; } u1, u2, u3;
#pragma unroll
    for (int t = 0; t < 4; t++) {
        float a = f[2 * t], b = f[2 * t + 1];
        unsigned int ua = __float_as_uint(a), ub = __float_as_uint(b);
        float da = a - __uint_as_float(ua & 0xFFFF0000u);
        float db = b - __uint_as_float(ub & 0xFFFF0000u);
        unsigned int uda = __float_as_uint(da), udb = __float_as_uint(db);
        float da2 = da - __uint_as_float(uda & 0xFFFF0000u);
        float db2 = db - __uint_as_float(udb & 0xFFFF0000u);
        u1.u[t] = (ua >> 16) | (ub & 0xFFFF0000u);
        u2.u[t] = (uda >> 16) | (udb & 0xFFFF0000u);
        u3.u[t] = (__float_as_uint(da2) >> 16) | (__float_as_uint(db2) & 0xFFFF0000u);
    }
    o1 = u1.v; o2 = u2.v; o3 = u3.v;
}

// ---- pre-kernel: split W into 3 bf16 planes in coalesced B-fragment layout ----
__global__ __launch_bounds__(64) void wsplit_kernel(const float* __restrict__ W,
                                                    char* __restrict__ wq,
                                                    float* __restrict__ wsf) {
    if (blockIdx.x < 3) wsf[blockIdx.x * 64 + threadIdx.x] = 0.f;   // zero accum[0,192)
    int idx8 = (blockIdx.x * 64 + threadIdx.x) * 8;   // 16384 threads x 8 elems
    int e = idx8 >> 11;
    int k0 = idx8 & 2047;                // octet-aligned k
    int c = k0 >> 6, ks = (k0 >> 4) & 3, half = (k0 >> 3) & 1;
    int g = e >> 5, l = (e & 31) + 32 * half;
    const float4* wp = (const float4*)(W + (size_t)e * HID + k0);
    float4 v0 = wp[0], v1 = wp[1];
    float f[8] = {v0.x, v0.y, v0.z, v0.w, v1.x, v1.y, v1.z, v1.w};
    unsigned int p1[4], p2[4], p3[4];
#pragma unroll
    for (int t = 0; t < 4; t++) {
        unsigned short a1, a2, a3, b1, b2, b3;
        split3(f[2 * t], a1, a2, a3);
        split3(f[2 * t + 1], b1, b2, b3);
        p1[t] = (unsigned int)a1 | ((unsigned int)b1 << 16);
        p2[t] = (unsigned int)a2 | ((unsigned int)b2 << 16);
        p3[t] = (unsigned int)a3 | ((unsigned int)b3 << 16);
    }
    char* base = wq + (size_t)(((c * 4 + ks) * 3 + 0) * 2 + g) * 1024 + l * 16;
    *(uint4*)(base)        = make_uint4(p1[0], p1[1], p1[2], p1[3]);   // plane 1
    *(uint4*)(base + 2048) = make_uint4(p2[0], p2[1], p2[2], p2[3]);   // plane 2
    *(uint4*)(base + 4096) = make_uint4(p3[0], p3[1], p3[2], p3[3]);   // plane 3
}

__global__ __launch_bounds__(NTHREADS, 4) void router_main(
    const float* __restrict__ x, const char* __restrict__ wq,
    float* __restrict__ out, float* __restrict__ wsf)
{
    // wave-private x staging: [wave][2 bufs][32 rows x 128 B], linear dest,
    // source granule pre-swizzled g^(row&7); frag reads use the same XOR -> <=4-way banks
    __shared__ __align__(16) char xs[8][2][4096];   // 64 KB
    __shared__ float slab[TM * 68];                 // 8.7 KB accumulated logits
    __shared__ float scount[NEXP];
    __shared__ float sprob[NEXP];
    __shared__ int slast;

    const int tid = threadIdx.x;
    const int w = tid >> 6;        // wave id: owns chunks w*4..w*4+3 (cols [w*1024, w*1024+1024) bytes)
    const int lane = tid & 63;
    const int r = lane & 31;       // A row (token); B expert within group
    const int h = lane >> 5;       // k-octet half
    const int n0 = blockIdx.x * TM;

    // zero logit accumulator + stats
    for (int i = tid; i < TM * 68; i += NTHREADS) slab[i] = 0.f;
    if (tid < NEXP) { scount[tid] = 0.f; sprob[tid] = 0.f; }
    __syncthreads();

    // ---- staging geometry (per wave, 1 half-chunk = 32 rows x 128 B = 4 KB = 4 stage calls) ----
    // call q covers rows q*8 + (lane>>3); lane granule sg=lane&7; source granule sg^(row&7).
    const int srow = lane >> 3, sg = lane & 7;
    const char* gsrc = (const char*)x + (size_t)(n0 + srow) * (HID * 4)
                     + (size_t)w * 1024 + (((sg ^ srow)) << 4);      // + q*8*8192 + hcl*128
    char* myxs = (char*)&xs[w][0][0];

    // frag-read byte offsets inside a 4 KB buffer (row-major 128 B rows, XOR-swizzled granules)
    const int swz = r & 7;
    // ksl 0/1, pva granule ksl*4+h*2, pvb granule +1
    const int roA0 = r * 128 + (((0 * 4 + h * 2) ^ swz) << 4);
    const int roB0 = r * 128 + (((0 * 4 + h * 2 + 1) ^ swz) << 4);
    const int roA1 = r * 128 + (((1 * 4 + h * 2) ^ swz) << 4);
    const int roB1 = r * 128 + (((1 * 4 + h * 2 + 1) ^ swz) << 4);

    f32x16 acc0, acc1;
#pragma unroll
    for (int i = 0; i < 16; i++) { acc0[i] = 0.f; acc1[i] = 0.f; }

    // wq address helper: half-chunk hcl -> chunk c = w*4 + (hcl>>1), kstep = (hcl&1)*2 + ksl
    const char* wqb = wq + (size_t)(w * 4) * CHUNK_B + lane * 16;
#define WQ_ADDR(hcl, ksl) (wqb + (size_t)((hcl) >> 1) * CHUNK_B + (((hcl) & 1) * 2 + (ksl)) * 6144)

    // ---- prologue: issue wq(hc0, ksl0) + stage(hc0 -> buf0) ----
    bhalf8 B0[6];
#pragma unroll
    for (int p = 0; p < 3; p++) {
        B0[p]     = *(const bhalf8*)(WQ_ADDR(0, 0) + p * 2048);          // group 0
        B0[3 + p] = *(const bhalf8*)(WQ_ADDR(0, 0) + p * 2048 + 1024);   // group 1
    }
#pragma unroll
    for (int q = 0; q < 4; q++)
        stage1k(gsrc + (size_t)q * 8 * (HID * 4) + 0 * 128, myxs + q * 1024);

    // ---- main loop: 8 half-chunks per wave, no barriers, counted vmcnt ----
#pragma unroll 1
    for (int hcl = 0; hcl < 8; ++hcl) {
        const char* buf = myxs + (hcl & 1) * 4096;
        // issue wq(hc, ksl1)
        bhalf8 B1[6];
#pragma unroll
        for (int p = 0; p < 3; p++) {
            B1[p]     = *(const bhalf8*)(WQ_ADDR(hcl, 1) + p * 2048);
            B1[3 + p] = *(const bhalf8*)(WQ_ADDR(hcl, 1) + p * 2048 + 1024);
        }
        // issue stage(hc+1) into the other buffer
        if (hcl < 7) {
            char* nb = myxs + ((hcl + 1) & 1) * 4096;
#pragma unroll
            for (int q = 0; q < 4; q++)
                stage1k(gsrc + (size_t)q * 8 * (HID * 4) + (size_t)(hcl + 1) * 128, nb + q * 1024);
            asm volatile("s_waitcnt vmcnt(10)" ::: "memory");   // stage(hc) + wq(hc,k0) done
        } else {
            asm volatile("s_waitcnt vmcnt(6)" ::: "memory");    // tail: only B1 outstanding
        }
        __builtin_amdgcn_sched_barrier(0);

        // ---- ksl = 0 ----
        {
            float4 va = *(const float4*)(buf + roA0);
            float4 vb = *(const float4*)(buf + roB0);
            bhalf8 A1, A2, A3;
            xsplit(va, vb, A1, A2, A3);
            acc0 = __builtin_amdgcn_mfma_f32_32x32x16_bf16(A1, B0[0], acc0, 0, 0, 0);
            acc1 = __builtin_amdgcn_mfma_f32_32x32x16_bf16(A1, B0[3], acc1, 0, 0, 0);
            acc0 = __builtin_amdgcn_mfma_f32_32x32x16_bf16(A1, B0[1], acc0, 0, 0, 0);
            acc1 = __builtin_amdgcn_mfma_f32_32x32x16_bf16(A1, B0[4], acc1, 0, 0, 0);
            acc0 = __builtin_amdgcn_mfma_f32_32x32x16_bf16(A2, B0[0], acc0, 0, 0, 0);
            acc1 = __builtin_amdgcn_mfma_f32_32x32x16_bf16(A2, B0[3], acc1, 0, 0, 0);
            acc0 = __builtin_amdgcn_mfma_f32_32x32x16_bf16(A1, B0[2], acc0, 0, 0, 0);
            acc1 = __builtin_amdgcn_mfma_f32_32x32x16_bf16(A1, B0[5], acc1, 0, 0, 0);
            acc0 = __builtin_amdgcn_mfma_f32_32x32x16_bf16(A2, B0[1], acc0, 0, 0, 0);
            acc1 = __builtin_amdgcn_mfma_f32_32x32x16_bf16(A2, B0[4], acc1, 0, 0, 0);
            acc0 = __builtin_amdgcn_mfma_f32_32x32x16_bf16(A3, B0[0], acc0, 0, 0, 0);
            acc1 = __builtin_amdgcn_mfma_f32_32x32x16_bf16(A3, B0[3], acc1, 0, 0, 0);
        }
        // issue wq(hc+1, ksl0) for next iteration
        bhalf8 B0n[6];
        if (hcl < 7) {
#pragma unroll
            for (int p = 0; p < 3; p++) {
                B0n[p]     = *(const bhalf8*)(WQ_ADDR(hcl + 1, 0) + p * 2048);
                B0n[3 + p] = *(const bhalf8*)(WQ_ADDR(hcl + 1, 0) + p * 2048 + 1024);
            }
            asm volatile("s_waitcnt vmcnt(10)" ::: "memory");   // wq(hc,k1) done
        } else {
            asm volatile("s_waitcnt vmcnt(0)" ::: "memory");
        }
        __builtin_amdgcn_sched_barrier(0);

        // ---- ksl = 1 ----
        {
            float4 va = *(const float4*)(buf + roA1);
            float4 vb = *(const float4*)(buf + roB1);
            bhalf8 A1, A2, A3;
            xsplit(va, vb, A1, A2, A3);
            acc0 = __builtin_amdgcn_mfma_f32_32x32x16_bf16(A1, B1[0], acc0, 0, 0, 0);
            acc1 = __builtin_amdgcn_mfma_f32_32x32x16_bf16(A1, B1[3], acc1, 0, 0, 0);
            acc0 = __builtin_amdgcn_mfma_f32_32x32x16_bf16(A1, B1[1], acc0, 0, 0, 0);
            acc1 = __builtin_amdgcn_mfma_f32_32x32x16_bf16(A1, B1[4], acc1, 0, 0, 0);
            acc0 = __builtin_amdgcn_mfma_f32_32x32x16_bf16(A2, B1[0], acc0, 0, 0, 0);
            acc1 = __builtin_amdgcn_mfma_f32_32x32x16_bf16(A2, B1[3], acc1, 0, 0, 0);
            acc0 = __builtin_amdgcn_mfma_f32_32x32x16_bf16(A1, B1[2], acc0, 0, 0, 0);
            acc1 = __builtin_amdgcn_mfma_f32_32x32x16_bf16(A1, B1[5], acc1, 0, 0, 0);
            acc0 = __builtin_amdgcn_mfma_f32_32x32x16_bf16(A2, B1[1], acc0, 0, 0, 0);
            acc1 = __builtin_amdgcn_mfma_f32_32x32x16_bf16(A2, B1[4], acc1, 0, 0, 0);
            acc0 = __builtin_amdgcn_mfma_f32_32x32x16_bf16(A3, B1[0], acc0, 0, 0, 0);
            acc1 = __builtin_amdgcn_mfma_f32_32x32x16_bf16(A3, B1[3], acc1, 0, 0, 0);
        }
        if (hcl < 7) {
#pragma unroll
            for (int q = 0; q < 6; q++) B0[q] = B0n[q];
        }
    }
#undef WQ_ADDR

    // ---- combine: accumulate partial tiles via LDS atomics (2-way banks = free) ----
    // C/D 32x32 layout: col = lane&31, row = (reg&3) + 8*(reg>>2) + 4*(lane>>5)  [m74/m101]
#pragma unroll
    for (int reg = 0; reg < 16; reg++) {
        int row = (reg & 3) + 8 * (reg >> 2) + 4 * h;
        atomicAdd(&slab[row * 68 + r],      acc0[reg]);
        atomicAdd(&slab[row * 68 + 32 + r], acc1[reg]);
    }
    __syncthreads();

    // ---- wave-parallel epilogue: wave w handles tokens w*TPW .. w*TPW+3 ----
    const float* logits = slab;
    float pacc = 0.f;   // per-lane (expert=lane) softmax-prob sum over this wave's tokens
#pragma unroll 1
    for (int j = 0; j < TPW; j++) {
        const int t = w * TPW + j;
        const float v = logits[t * 68 + lane];
        float m1 = v, m2 = -3.4e38f;
        int i1 = lane, i2 = 0;
#pragma unroll
        for (int off = 32; off > 0; off >>= 1) {
            float om1 = __shfl_xor(m1, off);
            int   oi1 = __shfl_xor(i1, off);
            float om2 = __shfl_xor(m2, off);
            int   oi2 = __shfl_xor(i2, off);
            if (om1 > m1 || (om1 == m1 && oi1 < i1)) {
                if (m1 > om2 || (m1 == om2 && i1 < oi2)) { m2 = m1; i2 = i1; }
                else { m2 = om2; i2 = oi2; }
                m1 = om1; i1 = oi1;
            } else {
                if (om1 > m2 || (om1 == m2 && oi1 < i2)) { m2 = om1; i2 = oi1; }
            }
        }
        float pr = __expf(v - m1);
        float Z = pr;
#pragma unroll
        for (int off = 32; off > 0; off >>= 1) Z += __shfl_xor(Z, off);
        float invZ = 1.f / Z;
        pacc += pr * invZ;
        if (lane == 0) {
            float p1 = invZ;
            float p2 = __expf(m2 - m1) * invZ;
            float denom = p1 + p2 + 1e-6f;
            int n = n0 + t;
            out[2 * n + 0] = p1 / denom;
            out[2 * n + 1] = p2 / denom;
            out[OUT_IDX_OFF + 2 * n + 0] = (float)i1;
            out[OUT_IDX_OFF + 2 * n + 1] = (float)i2;
            atomicAdd(&scount[i1], 1.f);
            atomicAdd(&scount[i2], 1.f);
        }
    }
    atomicAdd(&sprob[lane], pacc);
    __syncthreads();

    if (tid < NEXP) {
        atomicAdd(&wsf[tid], sprob[tid]);
        atomicAdd(&wsf[NEXP + tid], scount[tid]);
    }

    // ---- last block computes aux loss + counts (fused router_finish) ----
    __threadfence();
    if (tid == 0) {
        unsigned prev = __hip_atomic_fetch_add((unsigned int*)(wsf + 2 * NEXP), 1u,
                                               __ATOMIC_ACQ_REL, __HIP_MEMORY_SCOPE_AGENT);
        slast = (prev == NBLK - 1) ? 1 : 0;
    }
    __syncthreads();
    if (slast && tid < NEXP) {
        const int e = tid;
        const float invN = 1.f / (float)NTOK;
        float ps = __hip_atomic_load(wsf + e, __ATOMIC_RELAXED, __HIP_MEMORY_SCOPE_AGENT);
        float cs = __hip_atomic_load(wsf + NEXP + e, __ATOMIC_RELAXED, __HIP_MEMORY_SCOPE_AGENT);
        out[OUT_CNT_OFF + e] = cs;
        float pv = ps * invN;
        float av = cs * invN;
        float v = pv * pv + av * av;
#pragma unroll
        for (int off = 32; off > 0; off >>= 1)
            v += __shfl_down(v, off);
        if (e == 0) out[OUT_AUX_OFF] = v * (float)NEXP;
    }
}

extern "C" void kernel_launch(void* const* d_in, const int* in_sizes, int n_in,
                              void* d_out, int out_size, void* d_ws, size_t ws_size,
                              hipStream_t stream)
{
    const float* x = (const float*)d_in[0];   // [4,4096,2048] f32
    const float* W = (const float*)d_in[1];   // [64,2048] f32
    float* out = (float*)d_out;
    float* wsf = (float*)d_ws;
    char* wq = (char*)d_ws + WS_W_OFF;        // W planes: 32 chunks x 24576 B = 768 KB

    wsplit_kernel<<<256, 64, 0, stream>>>(W, wq, wsf);   // also zeros accum+counter
    router_main<<<NBLK, NTHREADS, 0, stream>>>(x, wq, out, wsf);
}

// Round 6
// 313.416 us; speedup vs baseline: 1.0523x; 1.0523x over previous
//
#include <hip/hip_runtime.h>

#define HID 2048
#define NEXP 64
#define NTOK 16384
#define TM 32            // tokens per block (one 32-row MFMA tile)
#define NTHREADS 512     // 8 waves
#define TPW 4            // tokens per wave in epilogue (TM / 8)
#define NBLK (NTOK / TM) // 512
#define WS_W_OFF 1024    // W planes start here in d_ws
#define CHUNK_B 24576    // 4 ksteps * 3 planes * 2 halves * 1024 B

// out layout (f32): weights [0,32768) | indices [32768,65536) | aux 65536 | counts [65537,65601)
#define OUT_IDX_OFF (2 * NTOK)
#define OUT_AUX_OFF (4 * NTOK)
#define OUT_CNT_OFF (4 * NTOK + 1)

typedef __attribute__((ext_vector_type(8))) short bhalf8;    // 8 bf16 = 4 VGPRs (A/B frag)
typedef __attribute__((ext_vector_type(16))) float f32x16;   // 32x32 C/D frag

// Exact 3-way RNE bf16 split (for W, precomputed): v == h1+h2+h3 exactly.
__device__ __forceinline__ void split3(float v, unsigned short& h1, unsigned short& h2, unsigned short& h3) {
    unsigned int u = __float_as_uint(v);
    unsigned int r1 = (u + 0x7FFFu + ((u >> 16) & 1u)) & 0xFFFF0000u;
    float f1 = __uint_as_float(r1);
    float d1 = v - f1;
    unsigned int u2 = __float_as_uint(d1);
    unsigned int r2 = (u2 + 0x7FFFu + ((u2 >> 16) & 1u)) & 0xFFFF0000u;
    float f2 = __uint_as_float(r2);
    float d2 = d1 - f2;
    h1 = (unsigned short)(r1 >> 16);
    h2 = (unsigned short)(r2 >> 16);
    h3 = (unsigned short)(__float_as_uint(d2) >> 16);
}

// Truncating 3-plane split of 8 fp32 -> three bf16x8 A-frags, in registers.
__device__ __forceinline__ void xsplit(float4 va, float4 vb, bhalf8& o1, bhalf8& o2, bhalf8& o3) {
    float f[8] = {va.x, va.y, va.z, va.w, vb.x, vb.y, vb.z, vb.w};
    union U { bhalf8 v; unsigned int u[4]; } u1, u2, u3;
#pragma unroll
    for (int t = 0; t < 4; t++) {
        float a = f[2 * t], b = f[2 * t + 1];
        unsigned int ua = __float_as_uint(a), ub = __float_as_uint(b);
        float da = a - __uint_as_float(ua & 0xFFFF0000u);
        float db = b - __uint_as_float(ub & 0xFFFF0000u);
        unsigned int uda = __float_as_uint(da), udb = __float_as_uint(db);
        float da2 = da - __uint_as_float(uda & 0xFFFF0000u);
        float db2 = db - __uint_as_float(udb & 0xFFFF0000u);
        u1.u[t] = (ua >> 16) | (ub & 0xFFFF0000u);
        u2.u[t] = (uda >> 16) | (udb & 0xFFFF0000u);
        u3.u[t] = (__float_as_uint(da2) >> 16) | (__float_as_uint(db2) & 0xFFFF0000u);
    }
    o1 = u1.v; o2 = u2.v; o3 = u3.v;
}

// ---- pre-kernel: split W into 3 bf16 planes in coalesced B-fragment layout ----
__global__ __launch_bounds__(64) void wsplit_kernel(const float* __restrict__ W,
                                                    char* __restrict__ wq,
                                                    float* __restrict__ wsf) {
    if (blockIdx.x < 3) wsf[blockIdx.x * 64 + threadIdx.x] = 0.f;   // zero accum[0,192)
    int idx8 = (blockIdx.x * 64 + threadIdx.x) * 8;   // 16384 threads x 8 elems
    int e = idx8 >> 11;
    int k0 = idx8 & 2047;                // octet-aligned k
    int c = k0 >> 6, ks = (k0 >> 4) & 3, half = (k0 >> 3) & 1;
    int g = e >> 5, l = (e & 31) + 32 * half;
    const float4* wp = (const float4*)(W + (size_t)e * HID + k0);
    float4 v0 = wp[0], v1 = wp[1];
    float f[8] = {v0.x, v0.y, v0.z, v0.w, v1.x, v1.y, v1.z, v1.w};
    unsigned int p1[4], p2[4], p3[4];
#pragma unroll
    for (int t = 0; t < 4; t++) {
        unsigned short a1, a2, a3, b1, b2, b3;
        split3(f[2 * t], a1, a2, a3);
        split3(f[2 * t + 1], b1, b2, b3);
        p1[t] = (unsigned int)a1 | ((unsigned int)b1 << 16);
        p2[t] = (unsigned int)a2 | ((unsigned int)b2 << 16);
        p3[t] = (unsigned int)a3 | ((unsigned int)b3 << 16);
    }
    char* base = wq + (size_t)(((c * 4 + ks) * 3 + 0) * 2 + g) * 1024 + l * 16;
    *(uint4*)(base)        = make_uint4(p1[0], p1[1], p1[2], p1[3]);   // plane 1
    *(uint4*)(base + 2048) = make_uint4(p2[0], p2[1], p2[2], p2[3]);   // plane 2
    *(uint4*)(base + 4096) = make_uint4(p3[0], p3[1], p3[2], p3[3]);   // plane 3
}

__global__ __launch_bounds__(NTHREADS, 2) void router_main(
    const float* __restrict__ x, const char* __restrict__ wq,
    float* __restrict__ out, float* __restrict__ wsf)
{
    __shared__ float slab[TM * 68];    // 8.7 KB accumulated logits
    __shared__ float scount[NEXP];
    __shared__ float sprob[NEXP];
    __shared__ int slast;

    const int tid = threadIdx.x;
    const int w = tid >> 6;        // wave id: owns chunks w*4 .. w*4+3
    const int lane = tid & 63;
    const int r = lane & 31;       // A row (token); B expert within group
    const int h = lane >> 5;       // k-octet half
    const int n0 = blockIdx.x * TM;

    // zero logit accumulator + stats
    for (int i = tid; i < TM * 68; i += NTHREADS) slab[i] = 0.f;
    if (tid < NEXP) { scount[tid] = 0.f; sprob[tid] = 0.f; }
    __syncthreads();

    const float* xrow = x + (size_t)(n0 + r) * HID + h * 8;
    const char* wqb = wq + lane * 16;
    const int c0 = w * 4;

    f32x16 acc0, acc1;
#pragma unroll
    for (int i = 0; i < 16; i++) { acc0[i] = 0.f; acc1[i] = 0.f; }

    // 2-deep register pipeline, fully unrolled (all indices compile-time):
    // pa/pb[buf][ks]: x float4s for current/next chunk; Bw/Bn: current/next kstep's 6 B-frags
    float4 pa[2][4], pb[2][4];
    bhalf8 Bw[6], Bn[6];

    // ---- prologue: x(chunk c0) + wq(c0, ks0) ----
    {
        const float* xc = xrow + c0 * 64;
#pragma unroll
        for (int ks = 0; ks < 4; ks++) {
            pa[0][ks] = *(const float4*)(xc + ks * 16);
            pb[0][ks] = *(const float4*)(xc + ks * 16 + 4);
        }
        const char* wk = wqb + (size_t)c0 * CHUNK_B;
#pragma unroll
        for (int p = 0; p < 3; p++) {
            Bw[p]     = *(const bhalf8*)(wk + p * 2048);          // group 0, plane p
            Bw[3 + p] = *(const bhalf8*)(wk + p * 2048 + 1024);   // group 1, plane p
        }
    }

    // ---- main: 4 chunks fully unrolled, loads of i+1 issued before compute of i ----
#pragma unroll
    for (int ci = 0; ci < 4; ++ci) {
        const int c = c0 + ci;
        const int cb = ci & 1;
        // issue next chunk's 8 x-loads now (longest latency, hides under 4 ksteps of compute)
        if (ci < 3) {
            const int nb = cb ^ 1;
            const float* xn = xrow + (c + 1) * 64;
#pragma unroll
            for (int ks = 0; ks < 4; ks++) {
                pa[nb][ks] = *(const float4*)(xn + ks * 16);
                pb[nb][ks] = *(const float4*)(xn + ks * 16 + 4);
            }
        }
#pragma unroll
        for (int ks = 0; ks < 4; ++ks) {
            // issue next kstep's 6 wq loads before computing this kstep
            if (ks < 3) {
                const char* wk = wqb + (size_t)c * CHUNK_B + (ks + 1) * 6144;
#pragma unroll
                for (int p = 0; p < 3; p++) {
                    Bn[p]     = *(const bhalf8*)(wk + p * 2048);
                    Bn[3 + p] = *(const bhalf8*)(wk + p * 2048 + 1024);
                }
            } else if (ci < 3) {
                const char* wk = wqb + (size_t)(c + 1) * CHUNK_B;
#pragma unroll
                for (int p = 0; p < 3; p++) {
                    Bn[p]     = *(const bhalf8*)(wk + p * 2048);
                    Bn[3 + p] = *(const bhalf8*)(wk + p * 2048 + 1024);
                }
            }
            // compute this kstep (same accumulation order as the 77us baseline)
            bhalf8 A1, A2, A3;
            xsplit(pa[cb][ks], pb[cb][ks], A1, A2, A3);
            acc0 = __builtin_amdgcn_mfma_f32_32x32x16_bf16(A1, Bw[0], acc0, 0, 0, 0);
            acc1 = __builtin_amdgcn_mfma_f32_32x32x16_bf16(A1, Bw[3], acc1, 0, 0, 0);
            acc0 = __builtin_amdgcn_mfma_f32_32x32x16_bf16(A1, Bw[1], acc0, 0, 0, 0);
            acc1 = __builtin_amdgcn_mfma_f32_32x32x16_bf16(A1, Bw[4], acc1, 0, 0, 0);
            acc0 = __builtin_amdgcn_mfma_f32_32x32x16_bf16(A2, Bw[0], acc0, 0, 0, 0);
            acc1 = __builtin_amdgcn_mfma_f32_32x32x16_bf16(A2, Bw[3], acc1, 0, 0, 0);
            acc0 = __builtin_amdgcn_mfma_f32_32x32x16_bf16(A1, Bw[2], acc0, 0, 0, 0);
            acc1 = __builtin_amdgcn_mfma_f32_32x32x16_bf16(A1, Bw[5], acc1, 0, 0, 0);
            acc0 = __builtin_amdgcn_mfma_f32_32x32x16_bf16(A2, Bw[1], acc0, 0, 0, 0);
            acc1 = __builtin_amdgcn_mfma_f32_32x32x16_bf16(A2, Bw[4], acc1, 0, 0, 0);
            acc0 = __builtin_amdgcn_mfma_f32_32x32x16_bf16(A3, Bw[0], acc0, 0, 0, 0);
            acc1 = __builtin_amdgcn_mfma_f32_32x32x16_bf16(A3, Bw[3], acc1, 0, 0, 0);
            if (ks < 3 || ci < 3) {
#pragma unroll
                for (int q = 0; q < 6; q++) Bw[q] = Bn[q];
            }
        }
    }

    // ---- combine: accumulate partial tiles via LDS atomics (2-way banks = free) ----
    // C/D 32x32 layout: col = lane&31, row = (reg&3) + 8*(reg>>2) + 4*(lane>>5)  [m74/m101]
#pragma unroll
    for (int reg = 0; reg < 16; reg++) {
        int row = (reg & 3) + 8 * (reg >> 2) + 4 * h;
        atomicAdd(&slab[row * 68 + r],      acc0[reg]);
        atomicAdd(&slab[row * 68 + 32 + r], acc1[reg]);
    }
    __syncthreads();

    // ---- wave-parallel epilogue: wave w handles tokens w*TPW .. w*TPW+3 ----
    const float* logits = slab;
    float pacc = 0.f;   // per-lane (expert=lane) softmax-prob sum over this wave's tokens
#pragma unroll 1
    for (int j = 0; j < TPW; j++) {
        const int t = w * TPW + j;
        const float v = logits[t * 68 + lane];
        float m1 = v, m2 = -3.4e38f;
        int i1 = lane, i2 = 0;
#pragma unroll
        for (int off = 32; off > 0; off >>= 1) {
            float om1 = __shfl_xor(m1, off);
            int   oi1 = __shfl_xor(i1, off);
            float om2 = __shfl_xor(m2, off);
            int   oi2 = __shfl_xor(i2, off);
            if (om1 > m1 || (om1 == m1 && oi1 < i1)) {
                if (m1 > om2 || (m1 == om2 && i1 < oi2)) { m2 = m1; i2 = i1; }
                else { m2 = om2; i2 = oi2; }
                m1 = om1; i1 = oi1;
            } else {
                if (om1 > m2 || (om1 == m2 && oi1 < i2)) { m2 = om1; i2 = oi1; }
            }
        }
        float pr = __expf(v - m1);
        float Z = pr;
#pragma unroll
        for (int off = 32; off > 0; off >>= 1) Z += __shfl_xor(Z, off);
        float invZ = 1.f / Z;
        pacc += pr * invZ;
        if (lane == 0) {
            float p1 = invZ;
            float p2 = __expf(m2 - m1) * invZ;
            float denom = p1 + p2 + 1e-6f;
            int n = n0 + t;
            out[2 * n + 0] = p1 / denom;
            out[2 * n + 1] = p2 / denom;
            out[OUT_IDX_OFF + 2 * n + 0] = (float)i1;
            out[OUT_IDX_OFF + 2 * n + 1] = (float)i2;
            atomicAdd(&scount[i1], 1.f);
            atomicAdd(&scount[i2], 1.f);
        }
    }
    atomicAdd(&sprob[lane], pacc);
    __syncthreads();

    if (tid < NEXP) {
        atomicAdd(&wsf[tid], sprob[tid]);
        atomicAdd(&wsf[NEXP + tid], scount[tid]);
    }

    // ---- last block computes aux loss + counts (fused router_finish) ----
    __threadfence();
    if (tid == 0) {
        unsigned prev = __hip_atomic_fetch_add((unsigned int*)(wsf + 2 * NEXP), 1u,
                                               __ATOMIC_ACQ_REL, __HIP_MEMORY_SCOPE_AGENT);
        slast = (prev == NBLK - 1) ? 1 : 0;
    }
    __syncthreads();
    if (slast && tid < NEXP) {
        const int e = tid;
        const float invN = 1.f / (float)NTOK;
        float ps = __hip_atomic_load(wsf + e, __ATOMIC_RELAXED, __HIP_MEMORY_SCOPE_AGENT);
        float cs = __hip_atomic_load(wsf + NEXP + e, __ATOMIC_RELAXED, __HIP_MEMORY_SCOPE_AGENT);
        out[OUT_CNT_OFF + e] = cs;
        float pv = ps * invN;
        float av = cs * invN;
        float v = pv * pv + av * av;
#pragma unroll
        for (int off = 32; off > 0; off >>= 1)
            v += __shfl_down(v, off);
        if (e == 0) out[OUT_AUX_OFF] = v * (float)NEXP;
    }
}

extern "C" void kernel_launch(void* const* d_in, const int* in_sizes, int n_in,
                              void* d_out, int out_size, void* d_ws, size_t ws_size,
                              hipStream_t stream)
{
    const float* x = (const float*)d_in[0];   // [4,4096,2048] f32
    const float* W = (const float*)d_in[1];   // [64,2048] f32
    float* out = (float*)d_out;
    float* wsf = (float*)d_ws;
    char* wq = (char*)d_ws + WS_W_OFF;        // W planes: 32 chunks x 24576 B = 768 KB

    wsplit_kernel<<<256, 64, 0, stream>>>(W, wq, wsf);   // also zeros accum+counter
    router_main<<<NBLK, NTHREADS, 0, stream>>>(x, wq, out, wsf);
}

// Round 7
// 300.985 us; speedup vs baseline: 1.0958x; 1.0413x over previous
//
#include <hip/hip_runtime.h>

#define HID 2048
#define NEXP 64
#define NTOK 16384
#define TM 32            // tokens per block (one 32-row MFMA tile)
#define NTHREADS 512     // 8 waves
#define CPW 4            // chunks per wave (32 / 8 waves)
#define TPW 4            // tokens per wave in epilogue (TM / 8)
#define NBLK (NTOK / TM) // 512
#define WS_W_OFF 1024    // W planes start here in d_ws
#define CHUNK_B 24576    // 4 ksteps * 3 planes * 2 halves * 1024 B

// out layout (f32): weights [0,32768) | indices [32768,65536) | aux 65536 | counts [65537,65601)
#define OUT_IDX_OFF (2 * NTOK)
#define OUT_AUX_OFF (4 * NTOK)
#define OUT_CNT_OFF (4 * NTOK + 1)

typedef __attribute__((ext_vector_type(8))) short bhalf8;    // 8 bf16 = 4 VGPRs (A/B frag)
typedef __attribute__((ext_vector_type(16))) float f32x16;   // 32x32 C/D frag

// Exact 3-way RNE bf16 split (for W, precomputed): v == h1+h2+h3 exactly.
__device__ __forceinline__ void split3(float v, unsigned short& h1, unsigned short& h2, unsigned short& h3) {
    unsigned int u = __float_as_uint(v);
    unsigned int r1 = (u + 0x7FFFu + ((u >> 16) & 1u)) & 0xFFFF0000u;
    float f1 = __uint_as_float(r1);
    float d1 = v - f1;
    unsigned int u2 = __float_as_uint(d1);
    unsigned int r2 = (u2 + 0x7FFFu + ((u2 >> 16) & 1u)) & 0xFFFF0000u;
    float f2 = __uint_as_float(r2);
    float d2 = d1 - f2;
    h1 = (unsigned short)(r1 >> 16);
    h2 = (unsigned short)(r2 >> 16);
    h3 = (unsigned short)(__float_as_uint(d2) >> 16);
}

// Truncating 3-plane split of 8 fp32 -> three bf16x8 A-frags, in registers.
__device__ __forceinline__ void xsplit(float4 va, float4 vb, bhalf8& o1, bhalf8& o2, bhalf8& o3) {
    float f[8] = {va.x, va.y, va.z, va.w, vb.x, vb.y, vb.z, vb.w};
    union U { bhalf8 v; unsigned int u[4]; } u1, u2, u3;
#pragma unroll
    for (int t = 0; t < 4; t++) {
        float a = f[2 * t], b = f[2 * t + 1];
        unsigned int ua = __float_as_uint(a), ub = __float_as_uint(b);
        float da = a - __uint_as_float(ua & 0xFFFF0000u);
        float db = b - __uint_as_float(ub & 0xFFFF0000u);
        unsigned int uda = __float_as_uint(da), udb = __float_as_uint(db);
        float da2 = da - __uint_as_float(uda & 0xFFFF0000u);
        float db2 = db - __uint_as_float(udb & 0xFFFF0000u);
        u1.u[t] = (ua >> 16) | (ub & 0xFFFF0000u);
        u2.u[t] = (uda >> 16) | (udb & 0xFFFF0000u);
        u3.u[t] = (__float_as_uint(da2) >> 16) | (__float_as_uint(db2) & 0xFFFF0000u);
    }
    o1 = u1.v; o2 = u2.v; o3 = u3.v;
}

// ---- pre-kernel: split W into 3 bf16 planes in coalesced B-fragment layout ----
__global__ __launch_bounds__(64) void wsplit_kernel(const float* __restrict__ W,
                                                    char* __restrict__ wq,
                                                    float* __restrict__ wsf) {
    if (blockIdx.x < 3) wsf[blockIdx.x * 64 + threadIdx.x] = 0.f;   // zero accum[0,192)
    int idx8 = (blockIdx.x * 64 + threadIdx.x) * 8;   // 16384 threads x 8 elems
    int e = idx8 >> 11;
    int k0 = idx8 & 2047;                // octet-aligned k
    int c = k0 >> 6, ks = (k0 >> 4) & 3, half = (k0 >> 3) & 1;
    int g = e >> 5, l = (e & 31) + 32 * half;
    const float4* wp = (const float4*)(W + (size_t)e * HID + k0);
    float4 v0 = wp[0], v1 = wp[1];
    float f[8] = {v0.x, v0.y, v0.z, v0.w, v1.x, v1.y, v1.z, v1.w};
    unsigned int p1[4], p2[4], p3[4];
#pragma unroll
    for (int t = 0; t < 4; t++) {
        unsigned short a1, a2, a3, b1, b2, b3;
        split3(f[2 * t], a1, a2, a3);
        split3(f[2 * t + 1], b1, b2, b3);
        p1[t] = (unsigned int)a1 | ((unsigned int)b1 << 16);
        p2[t] = (unsigned int)a2 | ((unsigned int)b2 << 16);
        p3[t] = (unsigned int)a3 | ((unsigned int)b3 << 16);
    }
    char* base = wq + (size_t)(((c * 4 + ks) * 3 + 0) * 2 + g) * 1024 + l * 16;
    *(uint4*)(base)        = make_uint4(p1[0], p1[1], p1[2], p1[3]);   // plane 1
    *(uint4*)(base + 2048) = make_uint4(p2[0], p2[1], p2[2], p2[3]);   // plane 2
    *(uint4*)(base + 4096) = make_uint4(p3[0], p3[1], p3[2], p3[3]);   // plane 3
}

// waves_per_eu(4,4): pin occupancy target at 4 waves/SIMD (2 blocks/CU) so the
// scheduler's VGPR pressure allowance is 128, not 64 -> load batches stay hoisted.
__global__ __launch_bounds__(NTHREADS)
__attribute__((amdgpu_waves_per_eu(4, 4)))
void router_main(
    const float* __restrict__ x, const char* __restrict__ wq,
    float* __restrict__ out, float* __restrict__ wsf)
{
    __shared__ float slab[TM * 68];    // 8.7 KB accumulated logits
    __shared__ float scount[NEXP];
    __shared__ float sprob[NEXP];
    __shared__ int slast;

    const int tid = threadIdx.x;
    const int w = tid >> 6;        // wave id: owns chunks w*CPW .. w*CPW+3
    const int lane = tid & 63;
    const int r = lane & 31;       // A row (token); B expert within group
    const int h = lane >> 5;       // k-octet half
    const int n0 = blockIdx.x * TM;

    // zero logit accumulator + stats
    for (int i = tid; i < TM * 68; i += NTHREADS) slab[i] = 0.f;
    if (tid < NEXP) { scount[tid] = 0.f; sprob[tid] = 0.f; }
    __syncthreads();

    const float* xrow = x + (size_t)(n0 + r) * HID + h * 8;

    f32x16 acc0, acc1;
#pragma unroll
    for (int i = 0; i < 16; i++) { acc0[i] = 0.f; acc1[i] = 0.f; }

    // ---- free-running K-loop (R1-verbatim): no LDS, no barriers, compiler-scheduled ----
#pragma unroll 1
    for (int i = 0; i < CPW; ++i) {
        const int c = w * CPW + i;
        const float* xc = xrow + c * 64;
        float4 pxa[4], pxb[4];
#pragma unroll
        for (int ks = 0; ks < 4; ks++) {
            pxa[ks] = *(const float4*)(xc + ks * 16);
            pxb[ks] = *(const float4*)(xc + ks * 16 + 4);
        }
        const char* wc = wq + (size_t)c * CHUNK_B + lane * 16;
#pragma unroll
        for (int ks = 0; ks < 4; ks++) {
            bhalf8 A1, A2, A3;
            xsplit(pxa[ks], pxb[ks], A1, A2, A3);
            const char* wk = wc + ks * 6144;
            // all 6 B-frags of this kstep up front -> scheduler can batch the loads
            bhalf8 B1 = *(const bhalf8*)(wk);
            bhalf8 B2 = *(const bhalf8*)(wk + 2048);
            bhalf8 B3 = *(const bhalf8*)(wk + 4096);
            bhalf8 C1 = *(const bhalf8*)(wk + 1024);
            bhalf8 C2 = *(const bhalf8*)(wk + 2048 + 1024);
            bhalf8 C3 = *(const bhalf8*)(wk + 4096 + 1024);
            acc0 = __builtin_amdgcn_mfma_f32_32x32x16_bf16(A1, B1, acc0, 0, 0, 0);
            acc0 = __builtin_amdgcn_mfma_f32_32x32x16_bf16(A1, B2, acc0, 0, 0, 0);
            acc0 = __builtin_amdgcn_mfma_f32_32x32x16_bf16(A2, B1, acc0, 0, 0, 0);
            acc0 = __builtin_amdgcn_mfma_f32_32x32x16_bf16(A1, B3, acc0, 0, 0, 0);
            acc0 = __builtin_amdgcn_mfma_f32_32x32x16_bf16(A2, B2, acc0, 0, 0, 0);
            acc0 = __builtin_amdgcn_mfma_f32_32x32x16_bf16(A3, B1, acc0, 0, 0, 0);
            acc1 = __builtin_amdgcn_mfma_f32_32x32x16_bf16(A1, C1, acc1, 0, 0, 0);
            acc1 = __builtin_amdgcn_mfma_f32_32x32x16_bf16(A1, C2, acc1, 0, 0, 0);
            acc1 = __builtin_amdgcn_mfma_f32_32x32x16_bf16(A2, C1, acc1, 0, 0, 0);
            acc1 = __builtin_amdgcn_mfma_f32_32x32x16_bf16(A1, C3, acc1, 0, 0, 0);
            acc1 = __builtin_amdgcn_mfma_f32_32x32x16_bf16(A2, C2, acc1, 0, 0, 0);
            acc1 = __builtin_amdgcn_mfma_f32_32x32x16_bf16(A3, C1, acc1, 0, 0, 0);
        }
    }

    // ---- combine: accumulate partial tiles via LDS atomics (2-way banks = free) ----
    // C/D 32x32 layout: col = lane&31, row = (reg&3) + 8*(reg>>2) + 4*(lane>>5)  [m74/m101]
#pragma unroll
    for (int reg = 0; reg < 16; reg++) {
        int row = (reg & 3) + 8 * (reg >> 2) + 4 * h;
        atomicAdd(&slab[row * 68 + r],      acc0[reg]);
        atomicAdd(&slab[row * 68 + 32 + r], acc1[reg]);
    }
    __syncthreads();

    // ---- wave-parallel epilogue: wave w handles tokens w*TPW .. w*TPW+3 ----
    const float* logits = slab;
    float pacc = 0.f;   // per-lane (expert=lane) softmax-prob sum over this wave's tokens
#pragma unroll 1
    for (int j = 0; j < TPW; j++) {
        const int t = w * TPW + j;
        const float v = logits[t * 68 + lane];
        float m1 = v, m2 = -3.4e38f;
        int i1 = lane, i2 = 0;
#pragma unroll
        for (int off = 32; off > 0; off >>= 1) {
            float om1 = __shfl_xor(m1, off);
            int   oi1 = __shfl_xor(i1, off);
            float om2 = __shfl_xor(m2, off);
            int   oi2 = __shfl_xor(i2, off);
            if (om1 > m1 || (om1 == m1 && oi1 < i1)) {
                if (m1 > om2 || (m1 == om2 && i1 < oi2)) { m2 = m1; i2 = i1; }
                else { m2 = om2; i2 = oi2; }
                m1 = om1; i1 = oi1;
            } else {
                if (om1 > m2 || (om1 == m2 && oi1 < i2)) { m2 = om1; i2 = oi1; }
            }
        }
        float pr = __expf(v - m1);
        float Z = pr;
#pragma unroll
        for (int off = 32; off > 0; off >>= 1) Z += __shfl_xor(Z, off);
        float invZ = 1.f / Z;
        pacc += pr * invZ;
        if (lane == 0) {
            float p1 = invZ;
            float p2 = __expf(m2 - m1) * invZ;
            float denom = p1 + p2 + 1e-6f;
            int n = n0 + t;
            out[2 * n + 0] = p1 / denom;
            out[2 * n + 1] = p2 / denom;
            out[OUT_IDX_OFF + 2 * n + 0] = (float)i1;
            out[OUT_IDX_OFF + 2 * n + 1] = (float)i2;
            atomicAdd(&scount[i1], 1.f);
            atomicAdd(&scount[i2], 1.f);
        }
    }
    atomicAdd(&sprob[lane], pacc);
    __syncthreads();

    if (tid < NEXP) {
        atomicAdd(&wsf[tid], sprob[tid]);
        atomicAdd(&wsf[NEXP + tid], scount[tid]);
    }

    // ---- last block computes aux loss + counts (fused router_finish) ----
    __threadfence();
    if (tid == 0) {
        unsigned prev = __hip_atomic_fetch_add((unsigned int*)(wsf + 2 * NEXP), 1u,
                                               __ATOMIC_ACQ_REL, __HIP_MEMORY_SCOPE_AGENT);
        slast = (prev == NBLK - 1) ? 1 : 0;
    }
    __syncthreads();
    if (slast && tid < NEXP) {
        const int e = tid;
        const float invN = 1.f / (float)NTOK;
        float ps = __hip_atomic_load(wsf + e, __ATOMIC_RELAXED, __HIP_MEMORY_SCOPE_AGENT);
        float cs = __hip_atomic_load(wsf + NEXP + e, __ATOMIC_RELAXED, __HIP_MEMORY_SCOPE_AGENT);
        out[OUT_CNT_OFF + e] = cs;
        float pv = ps * invN;
        float av = cs * invN;
        float v = pv * pv + av * av;
#pragma unroll
        for (int off = 32; off > 0; off >>= 1)
            v += __shfl_down(v, off);
        if (e == 0) out[OUT_AUX_OFF] = v * (float)NEXP;
    }
}

extern "C" void kernel_launch(void* const* d_in, const int* in_sizes, int n_in,
                              void* d_out, int out_size, void* d_ws, size_t ws_size,
                              hipStream_t stream)
{
    const float* x = (const float*)d_in[0];   // [4,4096,2048] f32
    const float* W = (const float*)d_in[1];   // [64,2048] f32
    float* out = (float*)d_out;
    float* wsf = (float*)d_ws;
    char* wq = (char*)d_ws + WS_W_OFF;        // W planes: 32 chunks x 24576 B = 768 KB

    wsplit_kernel<<<256, 64, 0, stream>>>(W, wq, wsf);   // also zeros accum+counter
    router_main<<<NBLK, NTHREADS, 0, stream>>>(x, wq, out, wsf);
}

// Round 8
// 218.893 us; speedup vs baseline: 1.5068x; 1.3750x over previous
//
#include <hip/hip_runtime.h>

#define HID 2048
#define NEXP 64
#define NTOK 16384
#define TM 32            // tokens per block (one 32-row MFMA tile)
#define NTHREADS 512     // 8 waves
#define KPH 8            // K-phases = waves per block
#define CPW 4            // chunks per wave (32 / KPH)
#define TPW 4            // tokens per wave in epilogue (TM / KPH)
#define WS_W_OFF 1024    // W planes start here in d_ws (accum in [0,512))
#define CHUNK_B 24576    // 4 ksteps * 3 planes * 2 halves * 1024 B

// out layout (f32): weights [0,32768) | indices [32768,65536) | aux 65536 | counts [65537,65601)
#define OUT_IDX_OFF (2 * NTOK)
#define OUT_AUX_OFF (4 * NTOK)
#define OUT_CNT_OFF (4 * NTOK + 1)

typedef __attribute__((ext_vector_type(8))) short bhalf8;    // 8 bf16 = 4 VGPRs (A/B frag)
typedef __attribute__((ext_vector_type(16))) float f32x16;   // 32x32 C/D frag

// Exact 3-way RNE bf16 split (for W, precomputed): v == h1+h2+h3 exactly.
__device__ __forceinline__ void split3(float v, unsigned short& h1, unsigned short& h2, unsigned short& h3) {
    unsigned int u = __float_as_uint(v);
    unsigned int r1 = (u + 0x7FFFu + ((u >> 16) & 1u)) & 0xFFFF0000u;
    float f1 = __uint_as_float(r1);
    float d1 = v - f1;
    unsigned int u2 = __float_as_uint(d1);
    unsigned int r2 = (u2 + 0x7FFFu + ((u2 >> 16) & 1u)) & 0xFFFF0000u;
    float f2 = __uint_as_float(r2);
    float d2 = d1 - f2;
    h1 = (unsigned short)(r1 >> 16);
    h2 = (unsigned short)(r2 >> 16);
    h3 = (unsigned short)(__float_as_uint(d2) >> 16);
}

// Truncating 3-plane split of 8 fp32 -> three bf16x8 A-frags, in registers.
__device__ __forceinline__ void xsplit(float4 va, float4 vb, bhalf8& o1, bhalf8& o2, bhalf8& o3) {
    float f[8] = {va.x, va.y, va.z, va.w, vb.x, vb.y, vb.z, vb.w};
    union U { bhalf8 v; unsigned int u[4]; } u1, u2, u3;
#pragma unroll
    for (int t = 0; t < 4; t++) {
        float a = f[2 * t], b = f[2 * t + 1];
        unsigned int ua = __float_as_uint(a), ub = __float_as_uint(b);
        float da = a - __uint_as_float(ua & 0xFFFF0000u);
        float db = b - __uint_as_float(ub & 0xFFFF0000u);
        unsigned int uda = __float_as_uint(da), udb = __float_as_uint(db);
        float da2 = da - __uint_as_float(uda & 0xFFFF0000u);
        float db2 = db - __uint_as_float(udb & 0xFFFF0000u);
        u1.u[t] = (ua >> 16) | (ub & 0xFFFF0000u);
        u2.u[t] = (uda >> 16) | (udb & 0xFFFF0000u);
        u3.u[t] = (__float_as_uint(da2) >> 16) | (__float_as_uint(db2) & 0xFFFF0000u);
    }
    o1 = u1.v; o2 = u2.v; o3 = u3.v;
}

// ---- pre-kernel: split W into 3 bf16 planes in coalesced B-fragment layout ----
__global__ __launch_bounds__(64) void wsplit_kernel(const float* __restrict__ W,
                                                    char* __restrict__ wq,
                                                    float* __restrict__ wsf) {
    if (blockIdx.x < 2) wsf[blockIdx.x * 64 + threadIdx.x] = 0.f;   // zero accum[0,128)
    int idx8 = (blockIdx.x * 64 + threadIdx.x) * 8;   // 16384 threads x 8 elems
    int e = idx8 >> 11;
    int k0 = idx8 & 2047;                // octet-aligned k
    int c = k0 >> 6, ks = (k0 >> 4) & 3, half = (k0 >> 3) & 1;
    int g = e >> 5, l = (e & 31) + 32 * half;
    const float4* wp = (const float4*)(W + (size_t)e * HID + k0);
    float4 v0 = wp[0], v1 = wp[1];
    float f[8] = {v0.x, v0.y, v0.z, v0.w, v1.x, v1.y, v1.z, v1.w};
    unsigned int p1[4], p2[4], p3[4];
#pragma unroll
    for (int t = 0; t < 4; t++) {
        unsigned short a1, a2, a3, b1, b2, b3;
        split3(f[2 * t], a1, a2, a3);
        split3(f[2 * t + 1], b1, b2, b3);
        p1[t] = (unsigned int)a1 | ((unsigned int)b1 << 16);
        p2[t] = (unsigned int)a2 | ((unsigned int)b2 << 16);
        p3[t] = (unsigned int)a3 | ((unsigned int)b3 << 16);
    }
    char* base = wq + (size_t)(((c * 4 + ks) * 3 + 0) * 2 + g) * 1024 + l * 16;
    *(uint4*)(base)        = make_uint4(p1[0], p1[1], p1[2], p1[3]);   // plane 1
    *(uint4*)(base + 2048) = make_uint4(p2[0], p2[1], p2[2], p2[3]);   // plane 2
    *(uint4*)(base + 4096) = make_uint4(p3[0], p3[1], p3[2], p3[3]);   // plane 3
}

__global__ __launch_bounds__(NTHREADS, 4) void router_main(
    const float* __restrict__ x, const char* __restrict__ wq,
    float* __restrict__ out, float* __restrict__ ws_accum)
{
    __shared__ float slab[KPH * TM * 68];   // 69632 B: per-kphase partial logits
    __shared__ float scount[NEXP];
    __shared__ float sprob[NEXP];

    const int tid = threadIdx.x;
    const int w = tid >> 6;        // kphase / wave id
    const int lane = tid & 63;
    const int r = lane & 31;       // A row / token within tile; B expert within group
    const int h = lane >> 5;       // k-octet half
    const int n0 = blockIdx.x * TM;

    const float* xrow = x + (size_t)(n0 + r) * HID + h * 8;

    f32x16 acc0, acc1;
#pragma unroll
    for (int i = 0; i < 16; i++) { acc0[i] = 0.f; acc1[i] = 0.f; }

    // ---- free-running K-loop: no LDS, no barriers ----
#pragma unroll 1
    for (int i = 0; i < CPW; ++i) {
        const int c = w * CPW + i;
        const float* xc = xrow + c * 64;
        float4 pxa[4], pxb[4];
#pragma unroll
        for (int ks = 0; ks < 4; ks++) {
            pxa[ks] = *(const float4*)(xc + ks * 16);
            pxb[ks] = *(const float4*)(xc + ks * 16 + 4);
        }
        const char* wc = wq + (size_t)c * CHUNK_B + lane * 16;
#pragma unroll
        for (int ks = 0; ks < 4; ks++) {
            bhalf8 A1, A2, A3;
            xsplit(pxa[ks], pxb[ks], A1, A2, A3);
            const char* wk = wc + ks * 6144;
            // all 6 B-frags of this kstep up front -> scheduler can batch the loads
            bhalf8 B1 = *(const bhalf8*)(wk);
            bhalf8 B2 = *(const bhalf8*)(wk + 2048);
            bhalf8 B3 = *(const bhalf8*)(wk + 4096);
            bhalf8 C1 = *(const bhalf8*)(wk + 1024);
            bhalf8 C2 = *(const bhalf8*)(wk + 2048 + 1024);
            bhalf8 C3 = *(const bhalf8*)(wk + 4096 + 1024);
            acc0 = __builtin_amdgcn_mfma_f32_32x32x16_bf16(A1, B1, acc0, 0, 0, 0);
            acc0 = __builtin_amdgcn_mfma_f32_32x32x16_bf16(A1, B2, acc0, 0, 0, 0);
            acc0 = __builtin_amdgcn_mfma_f32_32x32x16_bf16(A2, B1, acc0, 0, 0, 0);
            acc0 = __builtin_amdgcn_mfma_f32_32x32x16_bf16(A1, B3, acc0, 0, 0, 0);
            acc0 = __builtin_amdgcn_mfma_f32_32x32x16_bf16(A2, B2, acc0, 0, 0, 0);
            acc0 = __builtin_amdgcn_mfma_f32_32x32x16_bf16(A3, B1, acc0, 0, 0, 0);
            acc1 = __builtin_amdgcn_mfma_f32_32x32x16_bf16(A1, C1, acc1, 0, 0, 0);
            acc1 = __builtin_amdgcn_mfma_f32_32x32x16_bf16(A1, C2, acc1, 0, 0, 0);
            acc1 = __builtin_amdgcn_mfma_f32_32x32x16_bf16(A2, C1, acc1, 0, 0, 0);
            acc1 = __builtin_amdgcn_mfma_f32_32x32x16_bf16(A1, C3, acc1, 0, 0, 0);
            acc1 = __builtin_amdgcn_mfma_f32_32x32x16_bf16(A2, C2, acc1, 0, 0, 0);
            acc1 = __builtin_amdgcn_mfma_f32_32x32x16_bf16(A3, C1, acc1, 0, 0, 0);
        }
    }

    // ---- combine: each wave stores its partial tile to its slab ----
    // C/D 32x32 layout: col = lane&31, row = (reg&3) + 8*(reg>>2) + 4*(lane>>5)  [m74/m101]
#pragma unroll
    for (int reg = 0; reg < 16; reg++) {
        int row = (reg & 3) + 8 * (reg >> 2) + 4 * h;
        slab[(w * TM + row) * 68 + r]      = acc0[reg];
        slab[(w * TM + row) * 68 + 32 + r] = acc1[reg];
    }
    if (tid < NEXP) { scount[tid] = 0.f; sprob[tid] = 0.f; }
    __syncthreads();

    // reduce KPH kphase slabs into slab[0] (each (t,e) owned by exactly one thread)
    float* logits = slab;
#pragma unroll
    for (int idx = tid; idx < TM * NEXP; idx += NTHREADS) {
        int t = idx >> 6, e = idx & 63;
        float v = 0.f;
#pragma unroll
        for (int p = 0; p < KPH; p++) v += slab[(p * TM + t) * 68 + e];
        logits[t * 68 + e] = v;
    }
    __syncthreads();

    // ---- wave-parallel epilogue: wave w handles tokens w*TPW .. w*TPW+3 ----
    // lane = expert index; per token: 64-lane top-2 butterfly + wave-sum for Z.
    float pacc = 0.f;   // per-lane (expert=lane) sum over this wave's tokens of softmax prob
#pragma unroll 1
    for (int j = 0; j < TPW; j++) {
        const int t = w * TPW + j;
        const float v = logits[t * 68 + lane];
        float m1 = v, m2 = -3.4e38f;
        int i1 = lane, i2 = 0;
#pragma unroll
        for (int off = 32; off > 0; off >>= 1) {
            float om1 = __shfl_xor(m1, off);
            int   oi1 = __shfl_xor(i1, off);
            float om2 = __shfl_xor(m2, off);
            int   oi2 = __shfl_xor(i2, off);
            if (om1 > m1 || (om1 == m1 && oi1 < i1)) {
                // other's top wins; our old top competes for second
                if (m1 > om2 || (m1 == om2 && i1 < oi2)) { m2 = m1; i2 = i1; }
                else { m2 = om2; i2 = oi2; }
                m1 = om1; i1 = oi1;
            } else {
                if (om1 > m2 || (om1 == m2 && oi1 < i2)) { m2 = om1; i2 = oi1; }
            }
        }
        // all lanes converged on (m1,i1,m2,i2)
        float p = __expf(v - m1);
        float Z = p;
#pragma unroll
        for (int off = 32; off > 0; off >>= 1) Z += __shfl_xor(Z, off);
        float invZ = 1.f / Z;
        pacc += p * invZ;
        if (lane == 0) {
            float p1 = invZ;                       // exp(m1-m1)*invZ
            float p2 = __expf(m2 - m1) * invZ;
            float denom = p1 + p2 + 1e-6f;
            int n = n0 + t;
            out[2 * n + 0] = p1 / denom;
            out[2 * n + 1] = p2 / denom;
            out[OUT_IDX_OFF + 2 * n + 0] = (float)i1;
            out[OUT_IDX_OFF + 2 * n + 1] = (float)i2;
            atomicAdd(&scount[i1], 1.f);
            atomicAdd(&scount[i2], 1.f);
        }
    }
    atomicAdd(&sprob[lane], pacc);   // combine per-expert prob sums across 8 waves
    __syncthreads();

    if (tid < NEXP) {
        atomicAdd(&ws_accum[tid], sprob[tid]);
        atomicAdd(&ws_accum[NEXP + tid], scount[tid]);
    }
}

__global__ void router_finish(const float* __restrict__ ws_accum,
                              float* __restrict__ out)
{
    const int e = threadIdx.x;   // 64 threads = 1 wave
    const float invN = 1.f / (float)NTOK;
    float p = ws_accum[e] * invN;
    float a = ws_accum[NEXP + e] * invN;
    float v = p * p + a * a;
#pragma unroll
    for (int off = 32; off > 0; off >>= 1)
        v += __shfl_down(v, off);
    if (e == 0) out[OUT_AUX_OFF] = v * (float)NEXP;
    out[OUT_CNT_OFF + e] = ws_accum[NEXP + e];
}

extern "C" void kernel_launch(void* const* d_in, const int* in_sizes, int n_in,
                              void* d_out, int out_size, void* d_ws, size_t ws_size,
                              hipStream_t stream)
{
    const float* x = (const float*)d_in[0];   // [4,4096,2048] f32
    const float* W = (const float*)d_in[1];   // [64,2048] f32
    float* out = (float*)d_out;
    float* wsf = (float*)d_ws;
    char* wq = (char*)d_ws + WS_W_OFF;        // W planes: 32 chunks x 24576 B = 768 KB

    wsplit_kernel<<<256, 64, 0, stream>>>(W, wq, wsf);   // also zeros accum region
    router_main<<<NTOK / TM, NTHREADS, 0, stream>>>(x, wq, out, wsf);
    router_finish<<<1, 64, 0, stream>>>(wsf, out);
}